// Round 1
// baseline (639.430 us; speedup 1.0000x reference)
//
#include <hip/hip_runtime.h>
#include <cstdint>
#include <cstddef>

#define N_NODES 40000
#define N_EDGES 640000
#define CH 128
#define NL 3
#define NB 64
#define LN_EPS 1e-5f

// ---------------------------------------------------------------- utilities

__global__ void deg_kernel(const int* __restrict__ ei, int* __restrict__ degi) {
    int e = blockIdx.x * 256 + threadIdx.x;
    if (e < N_EDGES) atomicAdd(&degi[ei[N_EDGES + e]], 1);
}

__global__ void isq_kernel(const int* __restrict__ degi, float* __restrict__ isq) {
    int n = blockIdx.x * 256 + threadIdx.x;
    if (n < N_NODES) isq[n] = rsqrtf((float)degi[n] + 1.0f);
}

__global__ void scan1_kernel(const int* __restrict__ degi, int* __restrict__ rowptr,
                             int* __restrict__ bsum) {
    __shared__ int s[256];
    int t = threadIdx.x;
    int i = blockIdx.x * 256 + t;
    int v = (i < N_NODES) ? degi[i] : 0;
    s[t] = v;
    __syncthreads();
    for (int off = 1; off < 256; off <<= 1) {
        int add = (t >= off) ? s[t - off] : 0;
        __syncthreads();
        s[t] += add;
        __syncthreads();
    }
    if (i < N_NODES) rowptr[i + 1] = s[t];
    if (t == 255) bsum[blockIdx.x] = s[255];
}

__global__ void scan2_kernel(int* __restrict__ bsum, int* __restrict__ boff, int nb) {
    if (threadIdx.x == 0 && blockIdx.x == 0) {
        int a = 0;
        for (int j = 0; j < nb; ++j) { int v = bsum[j]; boff[j] = a; a += v; }
    }
}

__global__ void scan3_kernel(int* __restrict__ rowptr, const int* __restrict__ boff) {
    int i = blockIdx.x * 256 + threadIdx.x;
    if (i < N_NODES) rowptr[i + 1] += boff[blockIdx.x];
    if (i == 0 && blockIdx.x == 0) rowptr[0] = 0;
}

__global__ void fill_csr_kernel(const int* __restrict__ ei, const int* __restrict__ rowptr,
                                int* __restrict__ fill, int* __restrict__ srcs) {
    int e = blockIdx.x * 256 + threadIdx.x;
    if (e < N_EDGES) {
        int s = ei[e];
        int d = ei[N_EDGES + e];
        int pos = atomicAdd(&fill[d], 1);
        srcs[rowptr[d] + pos] = s;
    }
}

// ---------------------------------------------------------------- GEMM
// C = A[40000x128] @ W[128x128]  (+bias) (+relu | +residual)
// Block = 256 thr = 4 waves; tile = 64 rows x 128 cols; wave w -> cols [32w,32w+32)
// lane = row. W read wave-uniformly (s_load), A row streamed as float4 (L1 reuse
// across the 4 waves sharing the same 64 rows). 32 fp32 accumulators / thread.
template <int MODE>  // 0: (+bias), 1: bias+relu, 2: bias+residual
__launch_bounds__(256, 4)
__global__ void gemm128(const float* __restrict__ A, const float* __restrict__ W,
                        const float* __restrict__ bias, const float* __restrict__ Res,
                        float* __restrict__ Out) {
    const int lane = threadIdx.x & 63;
    const int wv = __builtin_amdgcn_readfirstlane((int)(threadIdx.x >> 6));
    const int colbase = wv * 32;
    const int row = blockIdx.x * 64 + lane;
    const float* arow = A + (size_t)row * CH;

    float acc[32];
#pragma unroll
    for (int c = 0; c < 32; ++c) acc[c] = bias ? bias[colbase + c] : 0.f;

    for (int kc = 0; kc < 32; ++kc) {
        float4 a4 = *(const float4*)(arow + kc * 4);
#pragma unroll
        for (int j = 0; j < 4; ++j) {
            float av = (&a4.x)[j];
            const float* wrow = W + (size_t)(kc * 4 + j) * CH + colbase;
#pragma unroll
            for (int c = 0; c < 32; ++c) acc[c] = fmaf(av, wrow[c], acc[c]);
        }
    }

    float* orow = Out + (size_t)row * CH + colbase;
    const float* rrow = Res + (size_t)row * CH + colbase;  // only deref if MODE==2
#pragma unroll
    for (int q = 0; q < 8; ++q) {
        float4 v;
        v.x = acc[q * 4 + 0]; v.y = acc[q * 4 + 1];
        v.z = acc[q * 4 + 2]; v.w = acc[q * 4 + 3];
        if (MODE == 1) {
            v.x = fmaxf(v.x, 0.f); v.y = fmaxf(v.y, 0.f);
            v.z = fmaxf(v.z, 0.f); v.w = fmaxf(v.w, 0.f);
        }
        if (MODE == 2) {
            float4 r = *(const float4*)(rrow + q * 4);
            v.x += r.x; v.y += r.y; v.z += r.z; v.w += r.w;
        }
        *(float4*)(orow + q * 4) = v;
    }
}

// ---------------------------------------------------------------- aggregation
// One wave per dst node. out = isq[d]*sum_{s in N(d)} isq[s]*hw[s] + isq[d]^2*hw[d] + b
__launch_bounds__(256)
__global__ void agg_kernel(const float* __restrict__ HW, const int* __restrict__ rowptr,
                           const int* __restrict__ srcs, const float* __restrict__ isq,
                           const float* __restrict__ bias, float* __restrict__ Out) {
    const int lane = threadIdx.x & 63;
    const int node = blockIdx.x * 4 + (threadIdx.x >> 6);
    const int start = rowptr[node];
    const int end = rowptr[node + 1];

    float ax = 0.f, ay = 0.f;
    for (int base = start; base < end; base += 64) {
        int idx = base + lane;
        int clamped = (idx < end) ? idx : (end - 1);
        int sl = srcs[clamped];
        float wl = isq[sl];
        int cnt = end - base;
        if (cnt > 64) cnt = 64;
        for (int j = 0; j < cnt; ++j) {
            int s = __shfl(sl, j);
            float w = __shfl(wl, j);
            const float2 v = *(const float2*)(HW + (size_t)s * CH + lane * 2);
            ax = fmaf(w, v.x, ax);
            ay = fmaf(w, v.y, ay);
        }
    }
    float d = isq[node];
    const float2 hv = *(const float2*)(HW + (size_t)node * CH + lane * 2);
    const float2 bb = *(const float2*)(bias + lane * 2);
    float2 o;
    o.x = d * ax + d * d * hv.x + bb.x;
    o.y = d * ay + d * d * hv.y + bb.y;
    *(float2*)(Out + (size_t)node * CH + lane * 2) = o;
}

// ---------------------------------------------------------------- layernorm
// RELURES=1: D = relu(LN(S)) + D   (in-place residual), else D = LN(S)
template <int RELURES>
__launch_bounds__(256)
__global__ void ln_kernel(float* __restrict__ D, const float* __restrict__ S,
                          const float* __restrict__ gamma, const float* __restrict__ beta) {
    const int lane = threadIdx.x & 63;
    const int node = blockIdx.x * 4 + (threadIdx.x >> 6);
    const float2 x = *(const float2*)(S + (size_t)node * CH + lane * 2);
    float sum = x.x + x.y;
    float sq = x.x * x.x + x.y * x.y;
    for (int m = 1; m < 64; m <<= 1) {
        sum += __shfl_xor(sum, m);
        sq += __shfl_xor(sq, m);
    }
    float mean = sum * (1.f / CH);
    float var = sq * (1.f / CH) - mean * mean;
    float rstd = rsqrtf(var + LN_EPS);
    const float2 gg = *(const float2*)(gamma + lane * 2);
    const float2 bb = *(const float2*)(beta + lane * 2);
    float y0 = (x.x - mean) * rstd * gg.x + bb.x;
    float y1 = (x.y - mean) * rstd * gg.y + bb.y;
    float2* dp = (float2*)(D + (size_t)node * CH + lane * 2);
    if (RELURES) {
        float2 r = *dp;
        y0 = fmaxf(y0, 0.f) + r.x;
        y1 = fmaxf(y1, 0.f) + r.y;
    }
    float2 o; o.x = y0; o.y = y1;
    *dp = o;
}

// ---------------------------------------------------------------- pooling
// batch is sorted; each wave sums a 16-node strip, flushing atomics per run.
__launch_bounds__(256)
__global__ void pool_kernel(const float* __restrict__ H, const int* __restrict__ batch,
                            float* __restrict__ g, float* __restrict__ cntf) {
    const int lane = threadIdx.x & 63;
    const int w = blockIdx.x * 4 + (threadIdx.x >> 6);
    const int n0 = w * 16;
    float lx = 0.f, ly = 0.f;
    int run = 0;
    int cur = batch[n0];
    for (int t = 0; t < 16; ++t) {
        int n = n0 + t;
        int b = batch[n];
        if (b != cur) {
            atomicAdd(&g[(size_t)cur * CH + lane * 2], lx);
            atomicAdd(&g[(size_t)cur * CH + lane * 2 + 1], ly);
            if (lane == 0) atomicAdd(&cntf[cur], (float)run);
            lx = ly = 0.f; run = 0; cur = b;
        }
        const float2 v = *(const float2*)(H + (size_t)n * CH + lane * 2);
        lx += v.x; ly += v.y; ++run;
    }
    atomicAdd(&g[(size_t)cur * CH + lane * 2], lx);
    atomicAdd(&g[(size_t)cur * CH + lane * 2 + 1], ly);
    if (lane == 0) atomicAdd(&cntf[cur], (float)run);
}

// ---------------------------------------------------------------- classifier
__launch_bounds__(128)
__global__ void cls_kernel(const float* __restrict__ g, const float* __restrict__ cntf,
                           const float* __restrict__ w1, const float* __restrict__ b1,
                           const float* __restrict__ w2, const float* __restrict__ b2,
                           float* __restrict__ out) {
    __shared__ float gm[CH];
    __shared__ float red[2];
    const int b = blockIdx.x;
    const int t = threadIdx.x;
    float inv = 1.f / fmaxf(cntf[b], 1.f);
    gm[t] = g[(size_t)b * CH + t] * inv;
    __syncthreads();
    float acc = b1[t];
    for (int k = 0; k < CH; ++k) acc = fmaf(gm[k], w1[(size_t)k * CH + t], acc);
    float v = fmaxf(acc, 0.f) * w2[t];
    for (int m = 1; m < 64; m <<= 1) v += __shfl_xor(v, m);
    if ((t & 63) == 0) red[t >> 6] = v;
    __syncthreads();
    if (t == 0) out[b] = red[0] + red[1] + b2[0];
}

// ---------------------------------------------------------------- launch

extern "C" void kernel_launch(void* const* d_in, const int* in_sizes, int n_in,
                              void* d_out, int out_size, void* d_ws, size_t ws_size,
                              hipStream_t stream) {
    const float* x      = (const float*)d_in[0];
    const int*   ei     = (const int*)d_in[1];
    const int*   batch  = (const int*)d_in[2];
    const float* pre_w  = (const float*)d_in[3];
    const float* pre_b  = (const float*)d_in[4];
    const float* conv_w = (const float*)d_in[5];
    const float* conv_b = (const float*)d_in[6];
    const float* ln_g   = (const float*)d_in[7];
    const float* ln_b   = (const float*)d_in[8];
    const float* ffn_w1 = (const float*)d_in[9];
    const float* ffn_b1 = (const float*)d_in[10];
    const float* ffn_w2 = (const float*)d_in[11];
    const float* ffn_b2 = (const float*)d_in[12];
    const float* fln_g  = (const float*)d_in[13];
    const float* fln_b  = (const float*)d_in[14];
    const float* cls_w1 = (const float*)d_in[15];
    const float* cls_b1 = (const float*)d_in[16];
    const float* cls_w2 = (const float*)d_in[17];
    const float* cls_b2 = (const float*)d_in[18];

    // workspace layout (~65 MB)
    float* H    = (float*)d_ws;
    float* HWb  = H + (size_t)N_NODES * CH;
    float* T    = HWb + (size_t)N_NODES * CH;
    int*   degi = (int*)(T + (size_t)N_NODES * CH);
    int*   fill = degi + N_NODES;
    float* g    = (float*)(fill + N_NODES);       // zero zone: degi..cntf contiguous
    float* cntf = g + (size_t)NB * CH;
    float* isq  = cntf + NB;
    int*  rowptr = (int*)(isq + N_NODES);
    int*  bsum   = rowptr + N_NODES + 1;
    int*  boff   = bsum + 256;
    int*  srcs   = boff + 256;

    const int nb_scan = (N_NODES + 255) / 256;  // 157

    // zero: degi, fill, g, cntf (contiguous)
    hipMemsetAsync(degi, 0, (size_t)(2 * N_NODES + NB * CH + NB) * sizeof(int), stream);

    deg_kernel<<<N_EDGES / 256, 256, 0, stream>>>(ei, degi);
    isq_kernel<<<nb_scan, 256, 0, stream>>>(degi, isq);
    scan1_kernel<<<nb_scan, 256, 0, stream>>>(degi, rowptr, bsum);
    scan2_kernel<<<1, 64, 0, stream>>>(bsum, boff, nb_scan);
    scan3_kernel<<<nb_scan, 256, 0, stream>>>(rowptr, boff);
    fill_csr_kernel<<<N_EDGES / 256, 256, 0, stream>>>(ei, rowptr, fill, srcs);

    // pre-scaler
    gemm128<0><<<N_NODES / 64, 256, 0, stream>>>(x, pre_w, pre_b, nullptr, H);

    for (int i = 0; i < NL; ++i) {
        gemm128<0><<<N_NODES / 64, 256, 0, stream>>>(H, conv_w + (size_t)i * CH * CH,
                                                     nullptr, nullptr, HWb);
        agg_kernel<<<N_NODES / 4, 256, 0, stream>>>(HWb, rowptr, srcs, isq,
                                                    conv_b + (size_t)i * CH, T);
        if (i < NL - 1) {
            // H = relu(LN(T)) + H
            ln_kernel<1><<<N_NODES / 4, 256, 0, stream>>>(H, T, ln_g + (size_t)i * CH,
                                                          ln_b + (size_t)i * CH);
            // T = relu(H @ w1 + b1)
            gemm128<1><<<N_NODES / 64, 256, 0, stream>>>(H, ffn_w1 + (size_t)i * CH * CH,
                                                         ffn_b1 + (size_t)i * CH, nullptr, T);
            // HW = T @ w2 + b2 + H
            gemm128<2><<<N_NODES / 64, 256, 0, stream>>>(T, ffn_w2 + (size_t)i * CH * CH,
                                                         ffn_b2 + (size_t)i * CH, H, HWb);
            // H = LN(HW)
            ln_kernel<0><<<N_NODES / 4, 256, 0, stream>>>(H, HWb, fln_g + (size_t)i * CH,
                                                          fln_b + (size_t)i * CH);
        }
    }

    pool_kernel<<<N_NODES / 64, 256, 0, stream>>>(T, batch, g, cntf);
    cls_kernel<<<NB, CH, 0, stream>>>(g, cntf, cls_w1, cls_b1, cls_w2, cls_b2,
                                      (float*)d_out);
}